// Round 12
// baseline (910.988 us; speedup 1.0000x reference)
//
#include <hip/hip_runtime.h>
#include <hip/hip_bf16.h>

// ---------------- problem constants ----------------
#define T_TOKENS 8192
#define HD 1024
#define FF 4096
#define NEXP 8
#define NR_MAX 17408   // 16384 picks + 8 experts * 127 max pad, rounded to 128

typedef __attribute__((ext_vector_type(8))) short bf16x8;
typedef __attribute__((ext_vector_type(4))) float f32x4;
typedef unsigned short ushort8v __attribute__((ext_vector_type(8)));

static __device__ __forceinline__ float b2f(ushort u) {
    union { unsigned u; float f; } c; c.u = ((unsigned)u) << 16; return c.f;
}
static __device__ __forceinline__ ushort f2b(float f) {
    union { float f; unsigned u; } c; c.f = f;
    unsigned r = c.u + 0x7fffu + ((c.u >> 16) & 1u);   // RNE
    return (ushort)(r >> 16);
}

// ---------------- L1: gate (blocks 0..2047)  ||  W1 transpose (blocks 2048..10239) ----------------
__global__ __launch_bounds__(256) void gate_w1t_kernel(
    const float* __restrict__ x, const float* __restrict__ Wg, const float* __restrict__ bg,
    float* __restrict__ logits, int* __restrict__ counts,
    int* __restrict__ e0a, int* __restrict__ e1a,
    float* __restrict__ w0a, float* __restrict__ w1a,
    const float* __restrict__ W1, ushort* __restrict__ W1T)
{
    __shared__ float tile[64][65];
    if (blockIdx.x < 2048) {
        // ---- gate path ----
        int t = blockIdx.x * 4 + (threadIdx.x >> 6);
        int l = threadIdx.x & 63;
        const float* xr = x + (size_t)t * HD;
        float acc[8] = {0,0,0,0,0,0,0,0};
        #pragma unroll
        for (int i = 0; i < 4; ++i) {
            int h0 = i * 256 + l * 4;
            float4 xv = *(const float4*)(xr + h0);
            #pragma unroll
            for (int j = 0; j < 4; ++j) {
                float xs = (&xv.x)[j];
                const float4* wr = (const float4*)(Wg + (size_t)(h0 + j) * NEXP);
                float4 wa = wr[0], wb = wr[1];
                acc[0] = fmaf(xs, wa.x, acc[0]);
                acc[1] = fmaf(xs, wa.y, acc[1]);
                acc[2] = fmaf(xs, wa.z, acc[2]);
                acc[3] = fmaf(xs, wa.w, acc[3]);
                acc[4] = fmaf(xs, wb.x, acc[4]);
                acc[5] = fmaf(xs, wb.y, acc[5]);
                acc[6] = fmaf(xs, wb.z, acc[6]);
                acc[7] = fmaf(xs, wb.w, acc[7]);
            }
        }
        #pragma unroll
        for (int off = 32; off > 0; off >>= 1) {
            #pragma unroll
            for (int e = 0; e < 8; ++e) acc[e] += __shfl_down(acc[e], off, 64);
        }
        if (l == 0) {
            float lg[8];
            #pragma unroll
            for (int e = 0; e < 8; ++e) {
                lg[e] = acc[e] + bg[e];
                logits[(size_t)t * NEXP + e] = lg[e];
            }
            float m = lg[0];
            #pragma unroll
            for (int e = 1; e < 8; ++e) m = fmaxf(m, lg[e]);
            float p[8], s = 0.f;
            #pragma unroll
            for (int e = 0; e < 8; ++e) { p[e] = expf(lg[e] - m); s += p[e]; }
            float inv = 1.f / s;
            #pragma unroll
            for (int e = 0; e < 8; ++e) p[e] *= inv;
            int i0 = 0;
            #pragma unroll
            for (int e = 1; e < 8; ++e) if (p[e] > p[i0]) i0 = e;
            int i1 = (i0 == 0) ? 1 : 0;
            #pragma unroll
            for (int e = 0; e < 8; ++e) if (e != i0 && p[e] > p[i1]) i1 = e;
            float ed = expf(p[i1] - p[i0]);          // <= 1
            float w0 = 1.f / (1.f + ed);
            float w1 = ed / (1.f + ed);
            e0a[t] = i0; e1a[t] = i1; w0a[t] = w0; w1a[t] = w1;
            atomicAdd(&counts[i0], 1);
            atomicAdd(&counts[i1], 1);
        }
    } else {
        // ---- W1 transpose path: [HD][FF] per expert -> [FF][HD] ----
        int bb = blockIdx.x - 2048;
        int e = bb >> 10, tid2 = bb & 1023;
        const float* in = W1 + (size_t)e * HD * FF;
        ushort* out = W1T + (size_t)e * HD * FF;
        int R = HD, C = FF;
        int rt = tid2 >> 6, ct = tid2 & 63;
        int r0 = rt * 64, c0 = ct * 64;

        int tr = threadIdx.x >> 4;
        int tc = (threadIdx.x & 15) * 4;
        #pragma unroll
        for (int i = 0; i < 4; ++i) {
            int r = tr + i * 16;
            float4 v = *(const float4*)(in + (size_t)(r0 + r) * C + c0 + tc);
            tile[r][tc + 0] = v.x;
            tile[r][tc + 1] = v.y;
            tile[r][tc + 2] = v.z;
            tile[r][tc + 3] = v.w;
        }
        __syncthreads();
        int cc = threadIdx.x >> 3;
        int rr = (threadIdx.x & 7) * 8;
        #pragma unroll
        for (int i = 0; i < 2; ++i) {
            int c = cc + i * 32;
            ushort8v o;
            #pragma unroll
            for (int j = 0; j < 8; ++j) o[j] = f2b(tile[rr + j][c]);
            *(ushort8v*)(out + (size_t)(c0 + c) * R + r0 + rr) = o;
        }
    }
}

// ---------------- assign+gather fused: 2 tokens/block ----------------
// Lane 0 of each 128-thread group claims rows via atomics, publishes rowtok/wrow;
// the group then copies x[t] -> Xp[r0], Xp[r1] as bf16. Padding rows stay garbage
// (provably dead: gemm2 scatter skips tok<0, H1 garbage rows never combined).
__global__ __launch_bounds__(256) void assign_gather_kernel(
    const float* __restrict__ x,
    const int* __restrict__ e0a, const int* __restrict__ e1a,
    const float* __restrict__ w0a, const float* __restrict__ w1a,
    const int* __restrict__ counts, int* __restrict__ fill, int* __restrict__ offg,
    int* __restrict__ row_token, float* __restrict__ wrow, ushort* __restrict__ Xp)
{
    __shared__ int off[9];
    __shared__ int rshare[2][2];
    if (threadIdx.x == 0) {
        int o = 0;
        #pragma unroll
        for (int e = 0; e < 8; ++e) { off[e] = o; o += (counts[e] + 127) & ~127; }
        off[8] = o;
        if (blockIdx.x == 0) {
            #pragma unroll
            for (int i = 0; i < 9; ++i) offg[i] = off[i];
        }
    }
    __syncthreads();
    int half = threadIdx.x >> 7;          // 0..1 (token within block)
    int lane = threadIdx.x & 127;
    int t = blockIdx.x * 2 + half;
    if (lane == 0) {
        int e0 = e0a[t];
        int r0 = off[e0] + atomicAdd(&fill[e0], 1);
        row_token[r0] = t; wrow[r0] = w0a[t]; rshare[half][0] = r0;
        int e1 = e1a[t];
        int r1 = off[e1] + atomicAdd(&fill[e1], 1);
        row_token[r1] = t; wrow[r1] = w1a[t]; rshare[half][1] = r1;
    }
    __syncthreads();
    int r0 = rshare[half][0], r1 = rshare[half][1];
    const float* src = x + (size_t)t * HD + lane * 8;
    float4 v1 = *(const float4*)(src);
    float4 v2 = *(const float4*)(src + 4);
    ushort8v o;
    o[0] = f2b(v1.x); o[1] = f2b(v1.y); o[2] = f2b(v1.z); o[3] = f2b(v1.w);
    o[4] = f2b(v2.x); o[5] = f2b(v2.y); o[6] = f2b(v2.z); o[7] = f2b(v2.w);
    *(ushort8v*)(Xp + (size_t)r0 * HD + lane * 8) = o;
    *(ushort8v*)(Xp + (size_t)r1 * HD + lane * 8) = o;
}

// ---------------- L4: GEMM1 (blocks 0..4351, r9-exact)  ||  W2 transpose (4352..12543) ----------------
__global__ __launch_bounds__(256, 4) void gemm1_w2t_kernel(
    const ushort* __restrict__ A, const ushort* __restrict__ Bt,
    const float* __restrict__ bias, ushort* __restrict__ Out,
    const int* __restrict__ off,
    const float* __restrict__ W2, ushort* __restrict__ W2T)
{
    constexpr int K = HD, NTOT = FF;
    constexpr int NT = NTOT / 128;                       // 32
    constexpr int NWG = (FF / 128) * (NR_MAX / 128);     // 4352
    __shared__ __align__(16) char smem[32768];

    if (blockIdx.x < NWG) {
        ushort* L = (ushort*)smem;
        constexpr int chunkc = NWG >> 3;                 // 544
        int cid = blockIdx.x & 7, q = blockIdx.x >> 3;
        constexpr int mloc = chunkc / NT;                // 17 (MFAST)
        int mtile = cid * mloc + q % mloc;
        int ntile = q / mloc;
        int r0 = mtile * 128;
        int total = off[8];
        if (r0 >= total) return;
        int e = 0;
        #pragma unroll
        for (int qq = 0; qq < 7; ++qq) if (r0 >= off[qq + 1]) e = qq + 1;

        int tid = threadIdx.x;
        int w = tid >> 6, lane = tid & 63;
        int wr = w >> 1, wc = w & 1;
        int lr = lane & 15, lk = lane >> 4;

        const ushort* Ab = A + (size_t)r0 * K;
        const ushort* Bb = Bt + ((size_t)e * NTOT + (size_t)ntile * 128) * K;

        auto stage = [&](const ushort* gbase, ushort* ldsbase) {
            #pragma unroll
            for (int issue = 0; issue < 2; ++issue) {
                int row = issue * 64 + w * 16 + (lane >> 2);
                int chunk = (lane & 3) ^ ((lane >> 3) & 3);
                const ushort* g = gbase + (size_t)row * K + chunk * 8;
                ushort* lp = ldsbase + (issue * 64 + w * 16) * 32;
                __builtin_amdgcn_global_load_lds(
                    (const __attribute__((address_space(1))) void*)g,
                    (__attribute__((address_space(3))) void*)lp, 16, 0, 0);
            }
        };

        stage(Ab, L + 0 * 4096);
        stage(Bb, L + 1 * 4096);

        f32x4 acc[4][4];
        #pragma unroll
        for (int mi = 0; mi < 4; ++mi)
            #pragma unroll
            for (int ni = 0; ni < 4; ++ni) acc[mi][ni] = (f32x4){0.f, 0.f, 0.f, 0.f};

        __syncthreads();

        constexpr int KT = K / 32;
        int cur = 0;
        int slot = lk ^ ((lr >> 1) & 3);
        for (int kt = 0; kt < KT; ++kt) {
            if (kt + 1 < KT) {
                stage(Ab + (kt + 1) * 32, L + ((cur ^ 1) * 2 + 0) * 4096);
                stage(Bb + (kt + 1) * 32, L + ((cur ^ 1) * 2 + 1) * 4096);
            }
            const ushort* As = L + (cur * 2 + 0) * 4096;
            const ushort* Bs = L + (cur * 2 + 1) * 4096;
            bf16x8 a[4], b[4];
            #pragma unroll
            for (int mi = 0; mi < 4; ++mi)
                a[mi] = *(const bf16x8*)(As + (wr * 64 + mi * 16 + lr) * 32 + slot * 8);
            #pragma unroll
            for (int ni = 0; ni < 4; ++ni)
                b[ni] = *(const bf16x8*)(Bs + (wc * 64 + ni * 16 + lr) * 32 + slot * 8);
            #pragma unroll
            for (int mi = 0; mi < 4; ++mi)
                #pragma unroll
                for (int ni = 0; ni < 4; ++ni)
                    acc[mi][ni] = __builtin_amdgcn_mfma_f32_16x16x32_bf16(
                        a[mi], b[ni], acc[mi][ni], 0, 0, 0);
            __syncthreads();
            cur ^= 1;
        }

        int c0 = ntile * 128 + wc * 64;
        int rbase = r0 + wr * 64;
        #pragma unroll
        for (int ni = 0; ni < 4; ++ni) {
            int n = c0 + ni * 16 + lr;
            float bv = bias[(size_t)e * NTOT + n];
            #pragma unroll
            for (int mi = 0; mi < 4; ++mi) {
                int m = rbase + mi * 16 + lk * 4;
                #pragma unroll
                for (int j = 0; j < 4; ++j) {
                    float v = acc[mi][ni][j] + bv;
                    v = fmaxf(v, 0.f);                    // ReLU
                    Out[(size_t)(m + j) * NTOT + n] = f2b(v);
                }
            }
        }
    } else {
        // ---- W2 transpose path: [FF][HD] per expert -> [HD][FF] ----
        float (*tile)[65] = (float(*)[65])smem;
        int bb = blockIdx.x - NWG;
        int e = bb >> 10, tid2 = bb & 1023;
        const float* in = W2 + (size_t)e * FF * HD;
        ushort* out = W2T + (size_t)e * FF * HD;
        int R = FF, C = HD;
        int rt = tid2 >> 4, ct = tid2 & 15;
        int r0 = rt * 64, c0 = ct * 64;

        int tr = threadIdx.x >> 4;
        int tc = (threadIdx.x & 15) * 4;
        #pragma unroll
        for (int i = 0; i < 4; ++i) {
            int r = tr + i * 16;
            float4 v = *(const float4*)(in + (size_t)(r0 + r) * C + c0 + tc);
            tile[r][tc + 0] = v.x;
            tile[r][tc + 1] = v.y;
            tile[r][tc + 2] = v.z;
            tile[r][tc + 3] = v.w;
        }
        __syncthreads();
        int cc = threadIdx.x >> 3;
        int rr = (threadIdx.x & 7) * 8;
        #pragma unroll
        for (int i = 0; i < 2; ++i) {
            int c = cc + i * 32;
            ushort8v o;
            #pragma unroll
            for (int j = 0; j < 8; ++j) o[j] = f2b(tile[rr + j][c]);
            *(ushort8v*)(out + (size_t)(c0 + c) * R + r0 + rr) = o;
        }
    }
}

// ---------------- GEMM2 + combine fused: r9 body, atomic-scatter epilogue ----------------
// out[tok] += wrow[m] * (acc + b2). Exactly 2 contributions per out element from a
// zeroed base; fp32 add is commutative -> result is order-independent (deterministic).
__global__ __launch_bounds__(256, 4) void gemm2_scatter_kernel(
    const ushort* __restrict__ A, const ushort* __restrict__ Bt,
    const float* __restrict__ bias,
    const int* __restrict__ rowtok, const float* __restrict__ wrow,
    float* __restrict__ out, const int* __restrict__ off)
{
    constexpr int K = FF, NTOT = HD;
    constexpr int NT = NTOT / 128;   // 8
    __shared__ __align__(16) ushort lds[2][2][128 * 32];

    int nwg = gridDim.x;
    int chunkc = nwg >> 3;
    int cid = blockIdx.x & 7, q = blockIdx.x >> 3;
    int wgid = cid * chunkc + q;
    int ntile = wgid % NT;
    int mtile = wgid / NT;
    int r0 = mtile * 128;
    int total = off[8];
    if (r0 >= total) return;
    int e = 0;
    #pragma unroll
    for (int qq = 0; qq < 7; ++qq) if (r0 >= off[qq + 1]) e = qq + 1;

    int tid = threadIdx.x;
    int w = tid >> 6, lane = tid & 63;
    int wr = w >> 1, wc = w & 1;
    int lr = lane & 15, lk = lane >> 4;

    const ushort* Ab = A + (size_t)r0 * K;
    const ushort* Bb = Bt + ((size_t)e * NTOT + (size_t)ntile * 128) * K;

    auto stage = [&](const ushort* gbase, ushort* ldsbase) {
        #pragma unroll
        for (int issue = 0; issue < 2; ++issue) {
            int row = issue * 64 + w * 16 + (lane >> 2);
            int chunk = (lane & 3) ^ ((lane >> 3) & 3);
            const ushort* g = gbase + (size_t)row * K + chunk * 8;
            ushort* lp = ldsbase + (issue * 64 + w * 16) * 32;
            __builtin_amdgcn_global_load_lds(
                (const __attribute__((address_space(1))) void*)g,
                (__attribute__((address_space(3))) void*)lp, 16, 0, 0);
        }
    };

    stage(Ab, &lds[0][0][0]);
    stage(Bb, &lds[0][1][0]);

    f32x4 acc[4][4];
    #pragma unroll
    for (int mi = 0; mi < 4; ++mi)
        #pragma unroll
        for (int ni = 0; ni < 4; ++ni) acc[mi][ni] = (f32x4){0.f, 0.f, 0.f, 0.f};

    __syncthreads();

    constexpr int KT = K / 32;
    int cur = 0;
    int slot = lk ^ ((lr >> 1) & 3);
    for (int kt = 0; kt < KT; ++kt) {
        if (kt + 1 < KT) {
            stage(Ab + (kt + 1) * 32, &lds[cur ^ 1][0][0]);
            stage(Bb + (kt + 1) * 32, &lds[cur ^ 1][1][0]);
        }
        const ushort* As = &lds[cur][0][0];
        const ushort* Bs = &lds[cur][1][0];
        bf16x8 a[4], b[4];
        #pragma unroll
        for (int mi = 0; mi < 4; ++mi)
            a[mi] = *(const bf16x8*)(As + (wr * 64 + mi * 16 + lr) * 32 + slot * 8);
        #pragma unroll
        for (int ni = 0; ni < 4; ++ni)
            b[ni] = *(const bf16x8*)(Bs + (wc * 64 + ni * 16 + lr) * 32 + slot * 8);
        #pragma unroll
        for (int mi = 0; mi < 4; ++mi)
            #pragma unroll
            for (int ni = 0; ni < 4; ++ni)
                acc[mi][ni] = __builtin_amdgcn_mfma_f32_16x16x32_bf16(
                    a[mi], b[ni], acc[mi][ni], 0, 0, 0);
        __syncthreads();
        cur ^= 1;
    }

    // stage rowtok/wrow for this 128-row tile into (now free) LDS
    int* toks = (int*)&lds[0][0][0];
    float* wvs = (float*)(&lds[0][0][0] + 4096);
    if (tid < 128) {
        toks[tid] = rowtok[r0 + tid];
        wvs[tid]  = wrow[r0 + tid];
    }
    __syncthreads();

    // epilogue: out[tok*HD + n] += w * (acc + bias). C/D map: col=lane&15, row=(lane>>4)*4+j
    int c0 = ntile * 128 + wc * 64;
    #pragma unroll
    for (int ni = 0; ni < 4; ++ni) {
        int n = c0 + ni * 16 + lr;
        float bv = bias[(size_t)e * NTOT + n];
        #pragma unroll
        for (int mi = 0; mi < 4; ++mi) {
            int mloc = wr * 64 + mi * 16 + lk * 4;
            #pragma unroll
            for (int j = 0; j < 4; ++j) {
                int tok = toks[mloc + j];
                if (tok >= 0) {
                    float v = wvs[mloc + j] * (acc[mi][ni][j] + bv);
                    atomicAdd(&out[(size_t)tok * HD + n], v);
                }
            }
        }
    }
}

// ---------------- workspace layout ----------------
#define WSA(x) (((x) + 255) & ~(size_t)255)
static constexpr size_t OFF_COUNTS = 0;
static constexpr size_t OFF_FILL   = 64;
static constexpr size_t OFF_OFF    = 128;
static constexpr size_t OFF_E0     = 256;
static constexpr size_t OFF_E1     = OFF_E0 + (size_t)T_TOKENS * 4;
static constexpr size_t OFF_W0     = OFF_E1 + (size_t)T_TOKENS * 4;
static constexpr size_t OFF_W1A    = OFF_W0 + (size_t)T_TOKENS * 4;
static constexpr size_t OFF_RT     = OFF_W1A + (size_t)T_TOKENS * 4;
static constexpr size_t OFF_WROW   = OFF_RT + (size_t)NR_MAX * 4;
static constexpr size_t OFF_XP     = WSA(OFF_WROW + (size_t)NR_MAX * 4);
static constexpr size_t OFF_W1T    = OFF_XP  + (size_t)NR_MAX * HD * 2;
static constexpr size_t OFF_W2T    = OFF_W1T + (size_t)NEXP * FF * HD * 2;
static constexpr size_t OFF_H1     = OFF_W2T + (size_t)NEXP * HD * FF * 2;
static constexpr size_t WS_NEEDED  = OFF_H1  + (size_t)NR_MAX * FF * 2;

extern "C" void kernel_launch(void* const* d_in, const int* in_sizes, int n_in,
                              void* d_out, int out_size, void* d_ws, size_t ws_size,
                              hipStream_t stream) {
    (void)in_sizes; (void)n_in; (void)out_size;
    const float* x  = (const float*)d_in[0];
    const float* Wg = (const float*)d_in[1];
    const float* bg = (const float*)d_in[2];
    const float* W1 = (const float*)d_in[3];
    const float* b1 = (const float*)d_in[4];
    const float* W2 = (const float*)d_in[5];
    const float* b2 = (const float*)d_in[6];
    float* out    = (float*)d_out;
    float* logits = out + (size_t)T_TOKENS * HD;

    if (ws_size < WS_NEEDED) return;  // need ~315 MB scratch

    char* ws = (char*)d_ws;
    int*    counts = (int*)(ws + OFF_COUNTS);
    int*    fill   = (int*)(ws + OFF_FILL);
    int*    offp   = (int*)(ws + OFF_OFF);
    int*    e0a    = (int*)(ws + OFF_E0);
    int*    e1a    = (int*)(ws + OFF_E1);
    float*  w0a    = (float*)(ws + OFF_W0);
    float*  w1a    = (float*)(ws + OFF_W1A);
    int*    rowtok = (int*)(ws + OFF_RT);
    float*  wrow   = (float*)(ws + OFF_WROW);
    ushort* Xp     = (ushort*)(ws + OFF_XP);
    ushort* W1T    = (ushort*)(ws + OFF_W1T);
    ushort* W2T    = (ushort*)(ws + OFF_W2T);
    ushort* H1     = (ushort*)(ws + OFF_H1);

    hipMemsetAsync(ws, 0, 256, stream);                              // counts/fill/off
    hipMemsetAsync(rowtok, 0xFF, (size_t)NR_MAX * 4, stream);        // row_token = -1
    hipMemsetAsync(out, 0, (size_t)T_TOKENS * HD * 4, stream);       // atomic accumulate base

    gate_w1t_kernel<<<2048 + 8192, 256, 0, stream>>>(
        x, Wg, bg, logits, counts, e0a, e1a, w0a, w1a, W1, W1T);
    assign_gather_kernel<<<T_TOKENS / 2, 256, 0, stream>>>(
        x, e0a, e1a, w0a, w1a, counts, fill, offp, rowtok, wrow, Xp);
    gemm1_w2t_kernel<<<(FF / 128) * (NR_MAX / 128) + 8192, 256, 0, stream>>>(
        Xp, W1T, b1, H1, offp, W2, W2T);
    gemm2_scatter_kernel<<<(HD / 128) * (NR_MAX / 128), 256, 0, stream>>>(
        H1, W2T, b2, rowtok, wrow, out, offp);
}

// Round 13
// 841.724 us; speedup vs baseline: 1.0823x; 1.0823x over previous
//
#include <hip/hip_runtime.h>
#include <hip/hip_bf16.h>

// ---------------- problem constants ----------------
#define T_TOKENS 8192
#define HD 1024
#define FF 4096
#define NEXP 8
#define NR_MAX 17408   // 16384 picks + 8 experts * 127 max pad, rounded to 128

typedef __attribute__((ext_vector_type(8))) short bf16x8;
typedef __attribute__((ext_vector_type(4))) float f32x4;
typedef unsigned short ushort8v __attribute__((ext_vector_type(8)));

static __device__ __forceinline__ float b2f(ushort u) {
    union { unsigned u; float f; } c; c.u = ((unsigned)u) << 16; return c.f;
}
static __device__ __forceinline__ ushort f2b(float f) {
    union { float f; unsigned u; } c; c.f = f;
    unsigned r = c.u + 0x7fffu + ((c.u >> 16) & 1u);   // RNE
    return (ushort)(r >> 16);
}

// ---------------- L1: gate (blocks 0..2047)  ||  W1 transpose (blocks 2048..10239) ----------------
__global__ __launch_bounds__(256) void gate_w1t_kernel(
    const float* __restrict__ x, const float* __restrict__ Wg, const float* __restrict__ bg,
    float* __restrict__ logits, int* __restrict__ counts,
    int* __restrict__ e0a, int* __restrict__ e1a,
    float* __restrict__ w0a, float* __restrict__ w1a,
    const float* __restrict__ W1, ushort* __restrict__ W1T)
{
    __shared__ float tile[64][65];
    if (blockIdx.x < 2048) {
        // ---- gate path ----
        int t = blockIdx.x * 4 + (threadIdx.x >> 6);
        int l = threadIdx.x & 63;
        const float* xr = x + (size_t)t * HD;
        float acc[8] = {0,0,0,0,0,0,0,0};
        #pragma unroll
        for (int i = 0; i < 4; ++i) {
            int h0 = i * 256 + l * 4;
            float4 xv = *(const float4*)(xr + h0);
            #pragma unroll
            for (int j = 0; j < 4; ++j) {
                float xs = (&xv.x)[j];
                const float4* wr = (const float4*)(Wg + (size_t)(h0 + j) * NEXP);
                float4 wa = wr[0], wb = wr[1];
                acc[0] = fmaf(xs, wa.x, acc[0]);
                acc[1] = fmaf(xs, wa.y, acc[1]);
                acc[2] = fmaf(xs, wa.z, acc[2]);
                acc[3] = fmaf(xs, wa.w, acc[3]);
                acc[4] = fmaf(xs, wb.x, acc[4]);
                acc[5] = fmaf(xs, wb.y, acc[5]);
                acc[6] = fmaf(xs, wb.z, acc[6]);
                acc[7] = fmaf(xs, wb.w, acc[7]);
            }
        }
        #pragma unroll
        for (int off = 32; off > 0; off >>= 1) {
            #pragma unroll
            for (int e = 0; e < 8; ++e) acc[e] += __shfl_down(acc[e], off, 64);
        }
        if (l == 0) {
            float lg[8];
            #pragma unroll
            for (int e = 0; e < 8; ++e) {
                lg[e] = acc[e] + bg[e];
                logits[(size_t)t * NEXP + e] = lg[e];
            }
            float m = lg[0];
            #pragma unroll
            for (int e = 1; e < 8; ++e) m = fmaxf(m, lg[e]);
            float p[8], s = 0.f;
            #pragma unroll
            for (int e = 0; e < 8; ++e) { p[e] = expf(lg[e] - m); s += p[e]; }
            float inv = 1.f / s;
            #pragma unroll
            for (int e = 0; e < 8; ++e) p[e] *= inv;
            int i0 = 0;
            #pragma unroll
            for (int e = 1; e < 8; ++e) if (p[e] > p[i0]) i0 = e;
            int i1 = (i0 == 0) ? 1 : 0;
            #pragma unroll
            for (int e = 0; e < 8; ++e) if (e != i0 && p[e] > p[i1]) i1 = e;
            float ed = expf(p[i1] - p[i0]);          // <= 1
            float w0 = 1.f / (1.f + ed);
            float w1 = ed / (1.f + ed);
            e0a[t] = i0; e1a[t] = i1; w0a[t] = w0; w1a[t] = w1;
            atomicAdd(&counts[i0], 1);
            atomicAdd(&counts[i1], 1);
        }
    } else {
        // ---- W1 transpose path: [HD][FF] per expert -> [FF][HD] ----
        int bb = blockIdx.x - 2048;
        int e = bb >> 10, tid2 = bb & 1023;
        const float* in = W1 + (size_t)e * HD * FF;
        ushort* out = W1T + (size_t)e * HD * FF;
        int R = HD, C = FF;
        int rt = tid2 >> 6, ct = tid2 & 63;
        int r0 = rt * 64, c0 = ct * 64;

        int tr = threadIdx.x >> 4;
        int tc = (threadIdx.x & 15) * 4;
        #pragma unroll
        for (int i = 0; i < 4; ++i) {
            int r = tr + i * 16;
            float4 v = *(const float4*)(in + (size_t)(r0 + r) * C + c0 + tc);
            tile[r][tc + 0] = v.x;
            tile[r][tc + 1] = v.y;
            tile[r][tc + 2] = v.z;
            tile[r][tc + 3] = v.w;
        }
        __syncthreads();
        int cc = threadIdx.x >> 3;
        int rr = (threadIdx.x & 7) * 8;
        #pragma unroll
        for (int i = 0; i < 2; ++i) {
            int c = cc + i * 32;
            ushort8v o;
            #pragma unroll
            for (int j = 0; j < 8; ++j) o[j] = f2b(tile[rr + j][c]);
            *(ushort8v*)(out + (size_t)(c0 + c) * R + r0 + rr) = o;
        }
    }
}

// ---------------- assign+gather fused: 2 tokens/block ----------------
// Lane 0 of each 128-thread group claims rows via atomics, publishes row0/row1;
// the group then converts x[t] once and stores bf16 to Xp[r0] and Xp[r1].
// Padding rows of Xp stay garbage (dead: combine reads only row0/row1 rows).
__global__ __launch_bounds__(256) void assign_gather_kernel(
    const float* __restrict__ x,
    const int* __restrict__ e0a, const int* __restrict__ e1a,
    const int* __restrict__ counts, int* __restrict__ fill, int* __restrict__ offg,
    int* __restrict__ row0, int* __restrict__ row1, ushort* __restrict__ Xp)
{
    __shared__ int off[9];
    __shared__ int rshare[2][2];
    if (threadIdx.x == 0) {
        int o = 0;
        #pragma unroll
        for (int e = 0; e < 8; ++e) { off[e] = o; o += (counts[e] + 127) & ~127; }
        off[8] = o;
        if (blockIdx.x == 0) {
            #pragma unroll
            for (int i = 0; i < 9; ++i) offg[i] = off[i];
        }
    }
    __syncthreads();
    int half = threadIdx.x >> 7;          // token within block
    int lane = threadIdx.x & 127;
    int t = blockIdx.x * 2 + half;
    if (lane == 0) {
        int e0 = e0a[t];
        int r0 = off[e0] + atomicAdd(&fill[e0], 1);
        row0[t] = r0; rshare[half][0] = r0;
        int e1 = e1a[t];
        int r1 = off[e1] + atomicAdd(&fill[e1], 1);
        row1[t] = r1; rshare[half][1] = r1;
    }
    __syncthreads();
    int r0 = rshare[half][0], r1 = rshare[half][1];
    const float* src = x + (size_t)t * HD + lane * 8;
    float4 v1 = *(const float4*)(src);
    float4 v2 = *(const float4*)(src + 4);
    ushort8v o;
    o[0] = f2b(v1.x); o[1] = f2b(v1.y); o[2] = f2b(v1.z); o[3] = f2b(v1.w);
    o[4] = f2b(v2.x); o[5] = f2b(v2.y); o[6] = f2b(v2.z); o[7] = f2b(v2.w);
    *(ushort8v*)(Xp + (size_t)r0 * HD + lane * 8) = o;
    *(ushort8v*)(Xp + (size_t)r1 * HD + lane * 8) = o;
}

// ---------------- L4: GEMM1 (blocks 0..4351, r9-exact)  ||  W2 transpose (4352..12543) ----------------
__global__ __launch_bounds__(256, 4) void gemm1_w2t_kernel(
    const ushort* __restrict__ A, const ushort* __restrict__ Bt,
    const float* __restrict__ bias, ushort* __restrict__ Out,
    const int* __restrict__ off,
    const float* __restrict__ W2, ushort* __restrict__ W2T)
{
    constexpr int K = HD, NTOT = FF;
    constexpr int NT = NTOT / 128;                       // 32
    constexpr int NWG = (FF / 128) * (NR_MAX / 128);     // 4352
    __shared__ __align__(16) char smem[32768];

    if (blockIdx.x < NWG) {
        ushort* L = (ushort*)smem;
        constexpr int chunkc = NWG >> 3;                 // 544
        int cid = blockIdx.x & 7, q = blockIdx.x >> 3;
        constexpr int mloc = chunkc / NT;                // 17 (MFAST)
        int mtile = cid * mloc + q % mloc;
        int ntile = q / mloc;
        int r0 = mtile * 128;
        int total = off[8];
        if (r0 >= total) return;
        int e = 0;
        #pragma unroll
        for (int qq = 0; qq < 7; ++qq) if (r0 >= off[qq + 1]) e = qq + 1;

        int tid = threadIdx.x;
        int w = tid >> 6, lane = tid & 63;
        int wr = w >> 1, wc = w & 1;
        int lr = lane & 15, lk = lane >> 4;

        const ushort* Ab = A + (size_t)r0 * K;
        const ushort* Bb = Bt + ((size_t)e * NTOT + (size_t)ntile * 128) * K;

        auto stage = [&](const ushort* gbase, ushort* ldsbase) {
            #pragma unroll
            for (int issue = 0; issue < 2; ++issue) {
                int row = issue * 64 + w * 16 + (lane >> 2);
                int chunk = (lane & 3) ^ ((lane >> 3) & 3);
                const ushort* g = gbase + (size_t)row * K + chunk * 8;
                ushort* lp = ldsbase + (issue * 64 + w * 16) * 32;
                __builtin_amdgcn_global_load_lds(
                    (const __attribute__((address_space(1))) void*)g,
                    (__attribute__((address_space(3))) void*)lp, 16, 0, 0);
            }
        };

        stage(Ab, L + 0 * 4096);
        stage(Bb, L + 1 * 4096);

        f32x4 acc[4][4];
        #pragma unroll
        for (int mi = 0; mi < 4; ++mi)
            #pragma unroll
            for (int ni = 0; ni < 4; ++ni) acc[mi][ni] = (f32x4){0.f, 0.f, 0.f, 0.f};

        __syncthreads();

        constexpr int KT = K / 32;
        int cur = 0;
        int slot = lk ^ ((lr >> 1) & 3);
        for (int kt = 0; kt < KT; ++kt) {
            if (kt + 1 < KT) {
                stage(Ab + (kt + 1) * 32, L + ((cur ^ 1) * 2 + 0) * 4096);
                stage(Bb + (kt + 1) * 32, L + ((cur ^ 1) * 2 + 1) * 4096);
            }
            const ushort* As = L + (cur * 2 + 0) * 4096;
            const ushort* Bs = L + (cur * 2 + 1) * 4096;
            bf16x8 a[4], b[4];
            #pragma unroll
            for (int mi = 0; mi < 4; ++mi)
                a[mi] = *(const bf16x8*)(As + (wr * 64 + mi * 16 + lr) * 32 + slot * 8);
            #pragma unroll
            for (int ni = 0; ni < 4; ++ni)
                b[ni] = *(const bf16x8*)(Bs + (wc * 64 + ni * 16 + lr) * 32 + slot * 8);
            #pragma unroll
            for (int mi = 0; mi < 4; ++mi)
                #pragma unroll
                for (int ni = 0; ni < 4; ++ni)
                    acc[mi][ni] = __builtin_amdgcn_mfma_f32_16x16x32_bf16(
                        a[mi], b[ni], acc[mi][ni], 0, 0, 0);
            __syncthreads();
            cur ^= 1;
        }

        int c0 = ntile * 128 + wc * 64;
        int rbase = r0 + wr * 64;
        #pragma unroll
        for (int ni = 0; ni < 4; ++ni) {
            int n = c0 + ni * 16 + lr;
            float bv = bias[(size_t)e * NTOT + n];
            #pragma unroll
            for (int mi = 0; mi < 4; ++mi) {
                int m = rbase + mi * 16 + lk * 4;
                #pragma unroll
                for (int j = 0; j < 4; ++j) {
                    float v = acc[mi][ni][j] + bv;
                    v = fmaxf(v, 0.f);                    // ReLU
                    Out[(size_t)(m + j) * NTOT + n] = f2b(v);
                }
            }
        }
    } else {
        // ---- W2 transpose path: [FF][HD] per expert -> [HD][FF] ----
        float (*tile)[65] = (float(*)[65])smem;
        int bb = blockIdx.x - NWG;
        int e = bb >> 10, tid2 = bb & 1023;
        const float* in = W2 + (size_t)e * FF * HD;
        ushort* out = W2T + (size_t)e * FF * HD;
        int R = FF, C = HD;
        int rt = tid2 >> 4, ct = tid2 & 15;
        int r0 = rt * 64, c0 = ct * 64;

        int tr = threadIdx.x >> 4;
        int tc = (threadIdx.x & 15) * 4;
        #pragma unroll
        for (int i = 0; i < 4; ++i) {
            int r = tr + i * 16;
            float4 v = *(const float4*)(in + (size_t)(r0 + r) * C + c0 + tc);
            tile[r][tc + 0] = v.x;
            tile[r][tc + 1] = v.y;
            tile[r][tc + 2] = v.z;
            tile[r][tc + 3] = v.w;
        }
        __syncthreads();
        int cc = threadIdx.x >> 3;
        int rr = (threadIdx.x & 7) * 8;
        #pragma unroll
        for (int i = 0; i < 2; ++i) {
            int c = cc + i * 32;
            ushort8v o;
            #pragma unroll
            for (int j = 0; j < 8; ++j) o[j] = f2b(tile[rr + j][c]);
            *(ushort8v*)(out + (size_t)(c0 + c) * R + r0 + rr) = o;
        }
    }
}

// ---------------- GEMM2: r9-proven 128x128 structure (n-fast XCD swizzle) ----------------
template<int K, int NTOT, bool RELU, bool MFAST>
__global__ __launch_bounds__(256, 4) void gemm_kernel(
    const ushort* __restrict__ A, const ushort* __restrict__ Bt,
    const float* __restrict__ bias, ushort* __restrict__ Out,
    const int* __restrict__ off)
{
    constexpr int NT = NTOT / 128;
    __shared__ __align__(16) ushort lds[2][2][128 * 32];

    int nwg = gridDim.x;
    int chunkc = nwg >> 3;
    int cid = blockIdx.x & 7, q = blockIdx.x >> 3;
    int mtile, ntile;
    if constexpr (MFAST) {
        int mloc = chunkc / NT;
        mtile = cid * mloc + q % mloc;
        ntile = q / mloc;
    } else {
        int wgid = cid * chunkc + q;
        ntile = wgid % NT;
        mtile = wgid / NT;
    }
    int r0 = mtile * 128;
    int total = off[8];
    if (r0 >= total) return;
    int e = 0;
    #pragma unroll
    for (int qq = 0; qq < 7; ++qq) if (r0 >= off[qq + 1]) e = qq + 1;

    int tid = threadIdx.x;
    int w = tid >> 6, lane = tid & 63;
    int wr = w >> 1, wc = w & 1;
    int lr = lane & 15, lk = lane >> 4;

    const ushort* Ab = A + (size_t)r0 * K;
    const ushort* Bb = Bt + ((size_t)e * NTOT + (size_t)ntile * 128) * K;

    auto stage = [&](const ushort* gbase, ushort* ldsbase) {
        #pragma unroll
        for (int issue = 0; issue < 2; ++issue) {
            int row = issue * 64 + w * 16 + (lane >> 2);
            int chunk = (lane & 3) ^ ((lane >> 3) & 3);
            const ushort* g = gbase + (size_t)row * K + chunk * 8;
            ushort* lp = ldsbase + (issue * 64 + w * 16) * 32;
            __builtin_amdgcn_global_load_lds(
                (const __attribute__((address_space(1))) void*)g,
                (__attribute__((address_space(3))) void*)lp, 16, 0, 0);
        }
    };

    stage(Ab, &lds[0][0][0]);
    stage(Bb, &lds[0][1][0]);

    f32x4 acc[4][4];
    #pragma unroll
    for (int mi = 0; mi < 4; ++mi)
        #pragma unroll
        for (int ni = 0; ni < 4; ++ni) acc[mi][ni] = (f32x4){0.f, 0.f, 0.f, 0.f};

    __syncthreads();

    constexpr int KT = K / 32;
    int cur = 0;
    int slot = lk ^ ((lr >> 1) & 3);
    for (int kt = 0; kt < KT; ++kt) {
        if (kt + 1 < KT) {
            stage(Ab + (kt + 1) * 32, &lds[cur ^ 1][0][0]);
            stage(Bb + (kt + 1) * 32, &lds[cur ^ 1][1][0]);
        }
        const ushort* As = &lds[cur][0][0];
        const ushort* Bs = &lds[cur][1][0];
        bf16x8 a[4], b[4];
        #pragma unroll
        for (int mi = 0; mi < 4; ++mi)
            a[mi] = *(const bf16x8*)(As + (wr * 64 + mi * 16 + lr) * 32 + slot * 8);
        #pragma unroll
        for (int ni = 0; ni < 4; ++ni)
            b[ni] = *(const bf16x8*)(Bs + (wc * 64 + ni * 16 + lr) * 32 + slot * 8);
        #pragma unroll
        for (int mi = 0; mi < 4; ++mi)
            #pragma unroll
            for (int ni = 0; ni < 4; ++ni)
                acc[mi][ni] = __builtin_amdgcn_mfma_f32_16x16x32_bf16(
                    a[mi], b[ni], acc[mi][ni], 0, 0, 0);
        __syncthreads();
        cur ^= 1;
    }

    int c0 = ntile * 128 + wc * 64;
    int rbase = r0 + wr * 64;
    #pragma unroll
    for (int ni = 0; ni < 4; ++ni) {
        int n = c0 + ni * 16 + lr;
        float bv = bias[(size_t)e * NTOT + n];
        #pragma unroll
        for (int mi = 0; mi < 4; ++mi) {
            int m = rbase + mi * 16 + lk * 4;
            #pragma unroll
            for (int j = 0; j < 4; ++j) {
                float v = acc[mi][ni][j] + bv;
                if (RELU) v = fmaxf(v, 0.f);
                Out[(size_t)(m + j) * NTOT + n] = f2b(v);
            }
        }
    }
}

// ---------------- combine: out[t] = w0*Y[r0] + w1*Y[r1]; 2 tokens/block, 16B/32B ----------------
__global__ __launch_bounds__(256) void combine_kernel(
    const ushort* __restrict__ Y, const int* __restrict__ row0, const int* __restrict__ row1,
    const float* __restrict__ w0a, const float* __restrict__ w1a, float* __restrict__ out)
{
    int half = threadIdx.x >> 7;
    int lane = threadIdx.x & 127;
    int t = blockIdx.x * 2 + half;
    int c = lane * 8;
    int r0 = row0[t], r1 = row1[t];
    float w0 = w0a[t], w1 = w1a[t];
    ushort8v ya = *(const ushort8v*)(Y + (size_t)r0 * HD + c);
    ushort8v yb = *(const ushort8v*)(Y + (size_t)r1 * HD + c);
    float4 o1, o2;
    o1.x = w0 * b2f(ya[0]) + w1 * b2f(yb[0]);
    o1.y = w0 * b2f(ya[1]) + w1 * b2f(yb[1]);
    o1.z = w0 * b2f(ya[2]) + w1 * b2f(yb[2]);
    o1.w = w0 * b2f(ya[3]) + w1 * b2f(yb[3]);
    o2.x = w0 * b2f(ya[4]) + w1 * b2f(yb[4]);
    o2.y = w0 * b2f(ya[5]) + w1 * b2f(yb[5]);
    o2.z = w0 * b2f(ya[6]) + w1 * b2f(yb[6]);
    o2.w = w0 * b2f(ya[7]) + w1 * b2f(yb[7]);
    float* dst = out + (size_t)t * HD + c;
    *(float4*)(dst) = o1;
    *(float4*)(dst + 4) = o2;
}

// ---------------- workspace layout ----------------
#define WSA(x) (((x) + 255) & ~(size_t)255)
static constexpr size_t OFF_COUNTS = 0;
static constexpr size_t OFF_FILL   = 64;
static constexpr size_t OFF_OFF    = 128;
static constexpr size_t OFF_E0     = 256;
static constexpr size_t OFF_E1     = OFF_E0 + (size_t)T_TOKENS * 4;
static constexpr size_t OFF_W0     = OFF_E1 + (size_t)T_TOKENS * 4;
static constexpr size_t OFF_W1A    = OFF_W0 + (size_t)T_TOKENS * 4;
static constexpr size_t OFF_R0     = OFF_W1A + (size_t)T_TOKENS * 4;
static constexpr size_t OFF_R1     = OFF_R0 + (size_t)T_TOKENS * 4;
static constexpr size_t OFF_XP     = WSA(OFF_R1 + (size_t)T_TOKENS * 4);
static constexpr size_t OFF_W1T    = OFF_XP  + (size_t)NR_MAX * HD * 2;
static constexpr size_t OFF_W2T    = OFF_W1T + (size_t)NEXP * FF * HD * 2;
static constexpr size_t OFF_H1     = OFF_W2T + (size_t)NEXP * HD * FF * 2;
static constexpr size_t OFF_Y      = OFF_H1  + (size_t)NR_MAX * FF * 2;
static constexpr size_t WS_NEEDED  = OFF_Y   + (size_t)NR_MAX * HD * 2;

extern "C" void kernel_launch(void* const* d_in, const int* in_sizes, int n_in,
                              void* d_out, int out_size, void* d_ws, size_t ws_size,
                              hipStream_t stream) {
    (void)in_sizes; (void)n_in; (void)out_size;
    const float* x  = (const float*)d_in[0];
    const float* Wg = (const float*)d_in[1];
    const float* bg = (const float*)d_in[2];
    const float* W1 = (const float*)d_in[3];
    const float* b1 = (const float*)d_in[4];
    const float* W2 = (const float*)d_in[5];
    const float* b2 = (const float*)d_in[6];
    float* out    = (float*)d_out;
    float* logits = out + (size_t)T_TOKENS * HD;

    if (ws_size < WS_NEEDED) return;  // need ~349 MB scratch

    char* ws = (char*)d_ws;
    int*    counts = (int*)(ws + OFF_COUNTS);
    int*    fill   = (int*)(ws + OFF_FILL);
    int*    offp   = (int*)(ws + OFF_OFF);
    int*    e0a    = (int*)(ws + OFF_E0);
    int*    e1a    = (int*)(ws + OFF_E1);
    float*  w0a    = (float*)(ws + OFF_W0);
    float*  w1a    = (float*)(ws + OFF_W1A);
    int*    row0   = (int*)(ws + OFF_R0);
    int*    row1   = (int*)(ws + OFF_R1);
    ushort* Xp     = (ushort*)(ws + OFF_XP);
    ushort* W1T    = (ushort*)(ws + OFF_W1T);
    ushort* W2T    = (ushort*)(ws + OFF_W2T);
    ushort* H1     = (ushort*)(ws + OFF_H1);
    ushort* Y      = (ushort*)(ws + OFF_Y);

    hipMemsetAsync(ws, 0, 256, stream);                         // counts/fill/off

    gate_w1t_kernel<<<2048 + 8192, 256, 0, stream>>>(
        x, Wg, bg, logits, counts, e0a, e1a, w0a, w1a, W1, W1T);
    assign_gather_kernel<<<T_TOKENS / 2, 256, 0, stream>>>(
        x, e0a, e1a, counts, fill, offp, row0, row1, Xp);
    gemm1_w2t_kernel<<<(FF / 128) * (NR_MAX / 128) + 8192, 256, 0, stream>>>(
        Xp, W1T, b1, H1, offp, W2, W2T);
    gemm_kernel<FF, HD, false, false>
        <<<(HD / 128) * (NR_MAX / 128), 256, 0, stream>>>(H1, W2T, b2, Y, offp);
    combine_kernel<<<T_TOKENS / 2, 256, 0, stream>>>(Y, row0, row1, w0a, w1a, out);
}

// Round 14
// 733.658 us; speedup vs baseline: 1.2417x; 1.1473x over previous
//
#include <hip/hip_runtime.h>
#include <hip/hip_bf16.h>

// ---------------- problem constants ----------------
#define T_TOKENS 8192
#define HD 1024
#define FF 4096
#define NEXP 8
#define NR_MAX 17408   // 16384 picks + 8 experts * 127 max pad, rounded to 128

typedef __attribute__((ext_vector_type(8))) short bf16x8;
typedef __attribute__((ext_vector_type(4))) float f32x4;
typedef unsigned short ushort8v __attribute__((ext_vector_type(8)));

static __device__ __forceinline__ float b2f(ushort u) {
    union { unsigned u; float f; } c; c.u = ((unsigned)u) << 16; return c.f;
}
static __device__ __forceinline__ ushort f2b(float f) {
    union { float f; unsigned u; } c; c.f = f;
    unsigned r = c.u + 0x7fffu + ((c.u >> 16) & 1u);   // RNE
    return (ushort)(r >> 16);
}

// ---------------- L1: gate (blocks 0..2047)  ||  W1 transpose (blocks 2048..10239) ----------------
// Independent: gate reads x/Wg; transpose reads W1. Gate hides under the transpose.
__global__ __launch_bounds__(256) void gate_w1t_kernel(
    const float* __restrict__ x, const float* __restrict__ Wg, const float* __restrict__ bg,
    float* __restrict__ logits, int* __restrict__ counts,
    int* __restrict__ e0a, int* __restrict__ e1a,
    float* __restrict__ w0a, float* __restrict__ w1a,
    const float* __restrict__ W1, ushort* __restrict__ W1T)
{
    __shared__ float tile[64][65];
    if (blockIdx.x < 2048) {
        // ---- gate path ----
        int t = blockIdx.x * 4 + (threadIdx.x >> 6);
        int l = threadIdx.x & 63;
        const float* xr = x + (size_t)t * HD;
        float acc[8] = {0,0,0,0,0,0,0,0};
        #pragma unroll
        for (int i = 0; i < 4; ++i) {
            int h0 = i * 256 + l * 4;
            float4 xv = *(const float4*)(xr + h0);
            #pragma unroll
            for (int j = 0; j < 4; ++j) {
                float xs = (&xv.x)[j];
                const float4* wr = (const float4*)(Wg + (size_t)(h0 + j) * NEXP);
                float4 wa = wr[0], wb = wr[1];
                acc[0] = fmaf(xs, wa.x, acc[0]);
                acc[1] = fmaf(xs, wa.y, acc[1]);
                acc[2] = fmaf(xs, wa.z, acc[2]);
                acc[3] = fmaf(xs, wa.w, acc[3]);
                acc[4] = fmaf(xs, wb.x, acc[4]);
                acc[5] = fmaf(xs, wb.y, acc[5]);
                acc[6] = fmaf(xs, wb.z, acc[6]);
                acc[7] = fmaf(xs, wb.w, acc[7]);
            }
        }
        #pragma unroll
        for (int off = 32; off > 0; off >>= 1) {
            #pragma unroll
            for (int e = 0; e < 8; ++e) acc[e] += __shfl_down(acc[e], off, 64);
        }
        if (l == 0) {
            float lg[8];
            #pragma unroll
            for (int e = 0; e < 8; ++e) {
                lg[e] = acc[e] + bg[e];
                logits[(size_t)t * NEXP + e] = lg[e];
            }
            float m = lg[0];
            #pragma unroll
            for (int e = 1; e < 8; ++e) m = fmaxf(m, lg[e]);
            float p[8], s = 0.f;
            #pragma unroll
            for (int e = 0; e < 8; ++e) { p[e] = expf(lg[e] - m); s += p[e]; }
            float inv = 1.f / s;
            #pragma unroll
            for (int e = 0; e < 8; ++e) p[e] *= inv;
            int i0 = 0;
            #pragma unroll
            for (int e = 1; e < 8; ++e) if (p[e] > p[i0]) i0 = e;
            int i1 = (i0 == 0) ? 1 : 0;
            #pragma unroll
            for (int e = 0; e < 8; ++e) if (e != i0 && p[e] > p[i1]) i1 = e;
            float ed = expf(p[i1] - p[i0]);          // <= 1
            float w0 = 1.f / (1.f + ed);
            float w1 = ed / (1.f + ed);
            e0a[t] = i0; e1a[t] = i1; w0a[t] = w0; w1a[t] = w1;
            atomicAdd(&counts[i0], 1);
            atomicAdd(&counts[i1], 1);
        }
    } else {
        // ---- W1 transpose path: [HD][FF] per expert -> [FF][HD] ----
        int bb = blockIdx.x - 2048;
        int e = bb >> 10, tid2 = bb & 1023;
        const float* in = W1 + (size_t)e * HD * FF;
        ushort* out = W1T + (size_t)e * HD * FF;
        int R = HD, C = FF;
        int rt = tid2 >> 6, ct = tid2 & 63;
        int r0 = rt * 64, c0 = ct * 64;

        int tr = threadIdx.x >> 4;
        int tc = (threadIdx.x & 15) * 4;
        #pragma unroll
        for (int i = 0; i < 4; ++i) {
            int r = tr + i * 16;
            float4 v = *(const float4*)(in + (size_t)(r0 + r) * C + c0 + tc);
            tile[r][tc + 0] = v.x;
            tile[r][tc + 1] = v.y;
            tile[r][tc + 2] = v.z;
            tile[r][tc + 3] = v.w;
        }
        __syncthreads();
        int cc = threadIdx.x >> 3;
        int rr = (threadIdx.x & 7) * 8;
        #pragma unroll
        for (int i = 0; i < 2; ++i) {
            int c = cc + i * 32;
            ushort8v o;
            #pragma unroll
            for (int j = 0; j < 8; ++j) o[j] = f2b(tile[rr + j][c]);
            *(ushort8v*)(out + (size_t)(c0 + c) * R + r0 + rr) = o;
        }
    }
}

// ---------------- assign rows (offsets folded in; block 0 publishes off[]) ----------------
__global__ __launch_bounds__(256) void assign_kernel(
    const int* __restrict__ e0a, const int* __restrict__ e1a,
    const int* __restrict__ counts, int* __restrict__ fill, int* __restrict__ offg,
    int* __restrict__ row0, int* __restrict__ row1, int* __restrict__ row_token)
{
    __shared__ int off[9];
    if (threadIdx.x == 0) {
        int o = 0;
        #pragma unroll
        for (int e = 0; e < 8; ++e) { off[e] = o; o += (counts[e] + 127) & ~127; }
        off[8] = o;
        if (blockIdx.x == 0) {
            #pragma unroll
            for (int i = 0; i < 9; ++i) offg[i] = off[i];
        }
    }
    __syncthreads();
    int t = blockIdx.x * 256 + threadIdx.x;
    if (t >= T_TOKENS) return;
    int e0 = e0a[t];
    int r0 = off[e0] + atomicAdd(&fill[e0], 1);
    row0[t] = r0; row_token[r0] = t;
    int e1 = e1a[t];
    int r1 = off[e1] + atomicAdd(&fill[e1], 1);
    row1[t] = r1; row_token[r1] = t;
}

// ---------------- gather x rows -> bf16 X_perm (zeros in padding rows) ----------------
__global__ __launch_bounds__(256) void gather_kernel(
    const float* __restrict__ x, const int* __restrict__ row_token, ushort* __restrict__ Xp)
{
    int r = blockIdx.x * 2 + (threadIdx.x >> 7);
    int c = (threadIdx.x & 127) * 8;
    int tok = row_token[r];
    ushort8v o;
    if (tok >= 0 && tok < T_TOKENS) {
        const float* src = x + (size_t)tok * HD + c;
        float4 v1 = *(const float4*)(src);
        float4 v2 = *(const float4*)(src + 4);
        o[0] = f2b(v1.x); o[1] = f2b(v1.y); o[2] = f2b(v1.z); o[3] = f2b(v1.w);
        o[4] = f2b(v2.x); o[5] = f2b(v2.y); o[6] = f2b(v2.z); o[7] = f2b(v2.w);
    } else {
        o = (ushort8v){0,0,0,0,0,0,0,0};
    }
    *(ushort8v*)(Xp + (size_t)r * HD + c) = o;
}

// ---------------- L4: GEMM1 (blocks 0..4351, r9-exact)  ||  W2 transpose (4352..12543) ----------------
// GEMM1 is latency-bound (13% HBM, 27% MfmaUtil) -> W2-transpose blocks backfill
// retiring CU slots and use the idle HBM BW. W2T consumed only by GEMM2 (next launch).
__global__ __launch_bounds__(256, 4) void gemm1_w2t_kernel(
    const ushort* __restrict__ A, const ushort* __restrict__ Bt,
    const float* __restrict__ bias, ushort* __restrict__ Out,
    const int* __restrict__ off,
    const float* __restrict__ W2, ushort* __restrict__ W2T)
{
    constexpr int K = HD, NTOT = FF;
    constexpr int NT = NTOT / 128;                       // 32
    constexpr int NWG = (FF / 128) * (NR_MAX / 128);     // 4352
    __shared__ __align__(16) char smem[32768];

    if (blockIdx.x < NWG) {
        // ---- GEMM1 path (r9-exact; lds via smem union) ----
        ushort* L = (ushort*)smem;                       // [2][2][4096] ushort
        constexpr int chunkc = NWG >> 3;                 // 544
        int cid = blockIdx.x & 7, q = blockIdx.x >> 3;
        constexpr int mloc = chunkc / NT;                // 17 (MFAST)
        int mtile = cid * mloc + q % mloc;
        int ntile = q / mloc;
        int r0 = mtile * 128;
        int total = off[8];
        if (r0 >= total) return;
        int e = 0;
        #pragma unroll
        for (int qq = 0; qq < 7; ++qq) if (r0 >= off[qq + 1]) e = qq + 1;

        int tid = threadIdx.x;
        int w = tid >> 6, lane = tid & 63;
        int wr = w >> 1, wc = w & 1;
        int lr = lane & 15, lk = lane >> 4;

        const ushort* Ab = A + (size_t)r0 * K;
        const ushort* Bb = Bt + ((size_t)e * NTOT + (size_t)ntile * 128) * K;

        auto stage = [&](const ushort* gbase, ushort* ldsbase) {
            #pragma unroll
            for (int issue = 0; issue < 2; ++issue) {
                int row = issue * 64 + w * 16 + (lane >> 2);
                int chunk = (lane & 3) ^ ((lane >> 3) & 3);
                const ushort* g = gbase + (size_t)row * K + chunk * 8;
                ushort* lp = ldsbase + (issue * 64 + w * 16) * 32;
                __builtin_amdgcn_global_load_lds(
                    (const __attribute__((address_space(1))) void*)g,
                    (__attribute__((address_space(3))) void*)lp, 16, 0, 0);
            }
        };

        stage(Ab, L + 0 * 4096);
        stage(Bb, L + 1 * 4096);

        f32x4 acc[4][4];
        #pragma unroll
        for (int mi = 0; mi < 4; ++mi)
            #pragma unroll
            for (int ni = 0; ni < 4; ++ni) acc[mi][ni] = (f32x4){0.f, 0.f, 0.f, 0.f};

        __syncthreads();

        constexpr int KT = K / 32;
        int cur = 0;
        int slot = lk ^ ((lr >> 1) & 3);
        for (int kt = 0; kt < KT; ++kt) {
            if (kt + 1 < KT) {
                stage(Ab + (kt + 1) * 32, L + ((cur ^ 1) * 2 + 0) * 4096);
                stage(Bb + (kt + 1) * 32, L + ((cur ^ 1) * 2 + 1) * 4096);
            }
            const ushort* As = L + (cur * 2 + 0) * 4096;
            const ushort* Bs = L + (cur * 2 + 1) * 4096;
            bf16x8 a[4], b[4];
            #pragma unroll
            for (int mi = 0; mi < 4; ++mi)
                a[mi] = *(const bf16x8*)(As + (wr * 64 + mi * 16 + lr) * 32 + slot * 8);
            #pragma unroll
            for (int ni = 0; ni < 4; ++ni)
                b[ni] = *(const bf16x8*)(Bs + (wc * 64 + ni * 16 + lr) * 32 + slot * 8);
            #pragma unroll
            for (int mi = 0; mi < 4; ++mi)
                #pragma unroll
                for (int ni = 0; ni < 4; ++ni)
                    acc[mi][ni] = __builtin_amdgcn_mfma_f32_16x16x32_bf16(
                        a[mi], b[ni], acc[mi][ni], 0, 0, 0);
            __syncthreads();
            cur ^= 1;
        }

        int c0 = ntile * 128 + wc * 64;
        int rbase = r0 + wr * 64;
        #pragma unroll
        for (int ni = 0; ni < 4; ++ni) {
            int n = c0 + ni * 16 + lr;
            float bv = bias[(size_t)e * NTOT + n];
            #pragma unroll
            for (int mi = 0; mi < 4; ++mi) {
                int m = rbase + mi * 16 + lk * 4;
                #pragma unroll
                for (int j = 0; j < 4; ++j) {
                    float v = acc[mi][ni][j] + bv;
                    v = fmaxf(v, 0.f);                    // ReLU
                    Out[(size_t)(m + j) * NTOT + n] = f2b(v);
                }
            }
        }
    } else {
        // ---- W2 transpose path: [FF][HD] per expert -> [HD][FF] ----
        float (*tile)[65] = (float(*)[65])smem;           // 64x65 fp32 = 16.6 KB
        int bb = blockIdx.x - NWG;
        int e = bb >> 10, tid2 = bb & 1023;
        const float* in = W2 + (size_t)e * FF * HD;
        ushort* out = W2T + (size_t)e * FF * HD;
        int R = FF, C = HD;
        int rt = tid2 >> 4, ct = tid2 & 15;
        int r0 = rt * 64, c0 = ct * 64;

        int tr = threadIdx.x >> 4;
        int tc = (threadIdx.x & 15) * 4;
        #pragma unroll
        for (int i = 0; i < 4; ++i) {
            int r = tr + i * 16;
            float4 v = *(const float4*)(in + (size_t)(r0 + r) * C + c0 + tc);
            tile[r][tc + 0] = v.x;
            tile[r][tc + 1] = v.y;
            tile[r][tc + 2] = v.z;
            tile[r][tc + 3] = v.w;
        }
        __syncthreads();
        int cc = threadIdx.x >> 3;
        int rr = (threadIdx.x & 7) * 8;
        #pragma unroll
        for (int i = 0; i < 2; ++i) {
            int c = cc + i * 32;
            ushort8v o;
            #pragma unroll
            for (int j = 0; j < 8; ++j) o[j] = f2b(tile[rr + j][c]);
            *(ushort8v*)(out + (size_t)(c0 + c) * R + r0 + rr) = o;
        }
    }
}

// ---------------- GEMM2: r9-proven 128x128 structure (n-fast XCD swizzle) ----------------
template<int K, int NTOT, bool RELU, bool MFAST>
__global__ __launch_bounds__(256, 4) void gemm_kernel(
    const ushort* __restrict__ A, const ushort* __restrict__ Bt,
    const float* __restrict__ bias, ushort* __restrict__ Out,
    const int* __restrict__ off)
{
    constexpr int NT = NTOT / 128;
    __shared__ __align__(16) ushort lds[2][2][128 * 32];

    int nwg = gridDim.x;
    int chunkc = nwg >> 3;
    int cid = blockIdx.x & 7, q = blockIdx.x >> 3;
    int mtile, ntile;
    if constexpr (MFAST) {
        int mloc = chunkc / NT;
        mtile = cid * mloc + q % mloc;
        ntile = q / mloc;
    } else {
        int wgid = cid * chunkc + q;
        ntile = wgid % NT;
        mtile = wgid / NT;
    }
    int r0 = mtile * 128;
    int total = off[8];
    if (r0 >= total) return;
    int e = 0;
    #pragma unroll
    for (int qq = 0; qq < 7; ++qq) if (r0 >= off[qq + 1]) e = qq + 1;

    int tid = threadIdx.x;
    int w = tid >> 6, lane = tid & 63;
    int wr = w >> 1, wc = w & 1;
    int lr = lane & 15, lk = lane >> 4;

    const ushort* Ab = A + (size_t)r0 * K;
    const ushort* Bb = Bt + ((size_t)e * NTOT + (size_t)ntile * 128) * K;

    auto stage = [&](const ushort* gbase, ushort* ldsbase) {
        #pragma unroll
        for (int issue = 0; issue < 2; ++issue) {
            int row = issue * 64 + w * 16 + (lane >> 2);
            int chunk = (lane & 3) ^ ((lane >> 3) & 3);
            const ushort* g = gbase + (size_t)row * K + chunk * 8;
            ushort* lp = ldsbase + (issue * 64 + w * 16) * 32;
            __builtin_amdgcn_global_load_lds(
                (const __attribute__((address_space(1))) void*)g,
                (__attribute__((address_space(3))) void*)lp, 16, 0, 0);
        }
    };

    stage(Ab, &lds[0][0][0]);
    stage(Bb, &lds[0][1][0]);

    f32x4 acc[4][4];
    #pragma unroll
    for (int mi = 0; mi < 4; ++mi)
        #pragma unroll
        for (int ni = 0; ni < 4; ++ni) acc[mi][ni] = (f32x4){0.f, 0.f, 0.f, 0.f};

    __syncthreads();

    constexpr int KT = K / 32;
    int cur = 0;
    int slot = lk ^ ((lr >> 1) & 3);
    for (int kt = 0; kt < KT; ++kt) {
        if (kt + 1 < KT) {
            stage(Ab + (kt + 1) * 32, &lds[cur ^ 1][0][0]);
            stage(Bb + (kt + 1) * 32, &lds[cur ^ 1][1][0]);
        }
        const ushort* As = &lds[cur][0][0];
        const ushort* Bs = &lds[cur][1][0];
        bf16x8 a[4], b[4];
        #pragma unroll
        for (int mi = 0; mi < 4; ++mi)
            a[mi] = *(const bf16x8*)(As + (wr * 64 + mi * 16 + lr) * 32 + slot * 8);
        #pragma unroll
        for (int ni = 0; ni < 4; ++ni)
            b[ni] = *(const bf16x8*)(Bs + (wc * 64 + ni * 16 + lr) * 32 + slot * 8);
        #pragma unroll
        for (int mi = 0; mi < 4; ++mi)
            #pragma unroll
            for (int ni = 0; ni < 4; ++ni)
                acc[mi][ni] = __builtin_amdgcn_mfma_f32_16x16x32_bf16(
                    a[mi], b[ni], acc[mi][ni], 0, 0, 0);
        __syncthreads();
        cur ^= 1;
    }

    int c0 = ntile * 128 + wc * 64;
    int rbase = r0 + wr * 64;
    #pragma unroll
    for (int ni = 0; ni < 4; ++ni) {
        int n = c0 + ni * 16 + lr;
        float bv = bias[(size_t)e * NTOT + n];
        #pragma unroll
        for (int mi = 0; mi < 4; ++mi) {
            int m = rbase + mi * 16 + lk * 4;
            #pragma unroll
            for (int j = 0; j < 4; ++j) {
                float v = acc[mi][ni][j] + bv;
                if (RELU) v = fmaxf(v, 0.f);
                Out[(size_t)(m + j) * NTOT + n] = f2b(v);
            }
        }
    }
}

// ---------------- combine: out[t] = w0*Y[r0] + w1*Y[r1] ----------------
__global__ __launch_bounds__(256) void combine_kernel(
    const ushort* __restrict__ Y, const int* __restrict__ row0, const int* __restrict__ row1,
    const float* __restrict__ w0a, const float* __restrict__ w1a, float* __restrict__ out)
{
    int t = blockIdx.x;
    int c = threadIdx.x * 4;
    int r0 = row0[t], r1 = row1[t];
    float w0 = w0a[t], w1 = w1a[t];
    ushort4 ya = *(const ushort4*)(Y + (size_t)r0 * HD + c);
    ushort4 yb = *(const ushort4*)(Y + (size_t)r1 * HD + c);
    float4 o;
    o.x = w0 * b2f(ya.x) + w1 * b2f(yb.x);
    o.y = w0 * b2f(ya.y) + w1 * b2f(yb.y);
    o.z = w0 * b2f(ya.z) + w1 * b2f(yb.z);
    o.w = w0 * b2f(ya.w) + w1 * b2f(yb.w);
    *(float4*)(out + (size_t)t * HD + c) = o;
}

// ---------------- workspace layout ----------------
#define WSA(x) (((x) + 255) & ~(size_t)255)
static constexpr size_t OFF_COUNTS = 0;
static constexpr size_t OFF_FILL   = 64;
static constexpr size_t OFF_OFF    = 128;
static constexpr size_t OFF_E0     = 256;
static constexpr size_t OFF_E1     = OFF_E0 + (size_t)T_TOKENS * 4;
static constexpr size_t OFF_W0     = OFF_E1 + (size_t)T_TOKENS * 4;
static constexpr size_t OFF_W1A    = OFF_W0 + (size_t)T_TOKENS * 4;
static constexpr size_t OFF_R0     = OFF_W1A + (size_t)T_TOKENS * 4;
static constexpr size_t OFF_R1     = OFF_R0 + (size_t)T_TOKENS * 4;
static constexpr size_t OFF_RT     = OFF_R1 + (size_t)T_TOKENS * 4;
static constexpr size_t OFF_XP     = WSA(OFF_RT + (size_t)NR_MAX * 4);
static constexpr size_t OFF_W1T    = OFF_XP  + (size_t)NR_MAX * HD * 2;
static constexpr size_t OFF_W2T    = OFF_W1T + (size_t)NEXP * FF * HD * 2;
static constexpr size_t OFF_H1     = OFF_W2T + (size_t)NEXP * HD * FF * 2;
static constexpr size_t OFF_Y      = OFF_H1  + (size_t)NR_MAX * FF * 2;
static constexpr size_t WS_NEEDED  = OFF_Y   + (size_t)NR_MAX * HD * 2;

extern "C" void kernel_launch(void* const* d_in, const int* in_sizes, int n_in,
                              void* d_out, int out_size, void* d_ws, size_t ws_size,
                              hipStream_t stream) {
    (void)in_sizes; (void)n_in; (void)out_size;
    const float* x  = (const float*)d_in[0];
    const float* Wg = (const float*)d_in[1];
    const float* bg = (const float*)d_in[2];
    const float* W1 = (const float*)d_in[3];
    const float* b1 = (const float*)d_in[4];
    const float* W2 = (const float*)d_in[5];
    const float* b2 = (const float*)d_in[6];
    float* out    = (float*)d_out;
    float* logits = out + (size_t)T_TOKENS * HD;

    if (ws_size < WS_NEEDED) return;  // need ~349 MB scratch

    char* ws = (char*)d_ws;
    int*    counts = (int*)(ws + OFF_COUNTS);
    int*    fill   = (int*)(ws + OFF_FILL);
    int*    offp   = (int*)(ws + OFF_OFF);
    int*    e0a    = (int*)(ws + OFF_E0);
    int*    e1a    = (int*)(ws + OFF_E1);
    float*  w0a    = (float*)(ws + OFF_W0);
    float*  w1a    = (float*)(ws + OFF_W1A);
    int*    row0   = (int*)(ws + OFF_R0);
    int*    row1   = (int*)(ws + OFF_R1);
    int*    rowtok = (int*)(ws + OFF_RT);
    ushort* Xp     = (ushort*)(ws + OFF_XP);
    ushort* W1T    = (ushort*)(ws + OFF_W1T);
    ushort* W2T    = (ushort*)(ws + OFF_W2T);
    ushort* H1     = (ushort*)(ws + OFF_H1);
    ushort* Y      = (ushort*)(ws + OFF_Y);

    hipMemsetAsync(ws, 0, 256, stream);                         // counts/fill/off
    hipMemsetAsync(rowtok, 0xFF, (size_t)NR_MAX * 4, stream);   // row_token = -1

    gate_w1t_kernel<<<2048 + 8192, 256, 0, stream>>>(
        x, Wg, bg, logits, counts, e0a, e1a, w0a, w1a, W1, W1T);
    assign_kernel<<<T_TOKENS / 256, 256, 0, stream>>>(e0a, e1a, counts, fill, offp, row0, row1, rowtok);
    gather_kernel<<<NR_MAX / 2, 256, 0, stream>>>(x, rowtok, Xp);
    gemm1_w2t_kernel<<<(FF / 128) * (NR_MAX / 128) + 8192, 256, 0, stream>>>(
        Xp, W1T, b1, H1, offp, W2, W2T);
    gemm_kernel<FF, HD, false, false>
        <<<(HD / 128) * (NR_MAX / 128), 256, 0, stream>>>(H1, W2T, b2, Y, offp);
    combine_kernel<<<T_TOKENS, 256, 0, stream>>>(Y, row0, row1, w0a, w1a, out);
}

// Round 15
// 723.444 us; speedup vs baseline: 1.2592x; 1.0141x over previous
//
#include <hip/hip_runtime.h>
#include <hip/hip_bf16.h>

// ---------------- problem constants ----------------
#define T_TOKENS 8192
#define HD 1024
#define FF 4096
#define NEXP 8
#define NR_MAX 17408   // 16384 picks + 8 experts * 127 max pad, rounded to 128

typedef __attribute__((ext_vector_type(8))) short bf16x8;
typedef __attribute__((ext_vector_type(4))) float f32x4;
typedef unsigned short ushort8v __attribute__((ext_vector_type(8)));

static __device__ __forceinline__ float b2f(ushort u) {
    union { unsigned u; float f; } c; c.u = ((unsigned)u) << 16; return c.f;
}
static __device__ __forceinline__ ushort f2b(float f) {
    union { float f; unsigned u; } c; c.f = f;
    unsigned r = c.u + 0x7fffu + ((c.u >> 16) & 1u);   // RNE
    return (ushort)(r >> 16);
}

// ---------------- L1: gate (blocks 0..2047)  ||  W1 transpose (blocks 2048..10239) ----------------
// Independent: gate reads x/Wg; transpose reads W1 (nontemporal: read-once stream).
__global__ __launch_bounds__(256) void gate_w1t_kernel(
    const float* __restrict__ x, const float* __restrict__ Wg, const float* __restrict__ bg,
    float* __restrict__ logits, int* __restrict__ counts,
    int* __restrict__ e0a, int* __restrict__ e1a,
    float* __restrict__ w0a, float* __restrict__ w1a,
    const float* __restrict__ W1, ushort* __restrict__ W1T)
{
    __shared__ float tile[64][65];
    if (blockIdx.x < 2048) {
        // ---- gate path ----
        int t = blockIdx.x * 4 + (threadIdx.x >> 6);
        int l = threadIdx.x & 63;
        const float* xr = x + (size_t)t * HD;
        float acc[8] = {0,0,0,0,0,0,0,0};
        #pragma unroll
        for (int i = 0; i < 4; ++i) {
            int h0 = i * 256 + l * 4;
            float4 xv = *(const float4*)(xr + h0);
            #pragma unroll
            for (int j = 0; j < 4; ++j) {
                float xs = (&xv.x)[j];
                const float4* wr = (const float4*)(Wg + (size_t)(h0 + j) * NEXP);
                float4 wa = wr[0], wb = wr[1];
                acc[0] = fmaf(xs, wa.x, acc[0]);
                acc[1] = fmaf(xs, wa.y, acc[1]);
                acc[2] = fmaf(xs, wa.z, acc[2]);
                acc[3] = fmaf(xs, wa.w, acc[3]);
                acc[4] = fmaf(xs, wb.x, acc[4]);
                acc[5] = fmaf(xs, wb.y, acc[5]);
                acc[6] = fmaf(xs, wb.z, acc[6]);
                acc[7] = fmaf(xs, wb.w, acc[7]);
            }
        }
        #pragma unroll
        for (int off = 32; off > 0; off >>= 1) {
            #pragma unroll
            for (int e = 0; e < 8; ++e) acc[e] += __shfl_down(acc[e], off, 64);
        }
        if (l == 0) {
            float lg[8];
            #pragma unroll
            for (int e = 0; e < 8; ++e) {
                lg[e] = acc[e] + bg[e];
                logits[(size_t)t * NEXP + e] = lg[e];
            }
            float m = lg[0];
            #pragma unroll
            for (int e = 1; e < 8; ++e) m = fmaxf(m, lg[e]);
            float p[8], s = 0.f;
            #pragma unroll
            for (int e = 0; e < 8; ++e) { p[e] = expf(lg[e] - m); s += p[e]; }
            float inv = 1.f / s;
            #pragma unroll
            for (int e = 0; e < 8; ++e) p[e] *= inv;
            int i0 = 0;
            #pragma unroll
            for (int e = 1; e < 8; ++e) if (p[e] > p[i0]) i0 = e;
            int i1 = (i0 == 0) ? 1 : 0;
            #pragma unroll
            for (int e = 0; e < 8; ++e) if (e != i0 && p[e] > p[i1]) i1 = e;
            float ed = expf(p[i1] - p[i0]);          // <= 1
            float w0 = 1.f / (1.f + ed);
            float w1 = ed / (1.f + ed);
            e0a[t] = i0; e1a[t] = i1; w0a[t] = w0; w1a[t] = w1;
            atomicAdd(&counts[i0], 1);
            atomicAdd(&counts[i1], 1);
        }
    } else {
        // ---- W1 transpose path: [HD][FF] per expert -> [FF][HD] ----
        int bb = blockIdx.x - 2048;
        int e = bb >> 10, tid2 = bb & 1023;
        const float* in = W1 + (size_t)e * HD * FF;
        ushort* out = W1T + (size_t)e * HD * FF;
        int R = HD, C = FF;
        int rt = tid2 >> 6, ct = tid2 & 63;
        int r0 = rt * 64, c0 = ct * 64;

        int tr = threadIdx.x >> 4;
        int tc = (threadIdx.x & 15) * 4;
        #pragma unroll
        for (int i = 0; i < 4; ++i) {
            int r = tr + i * 16;
            f32x4 v = __builtin_nontemporal_load(
                (const f32x4*)(in + (size_t)(r0 + r) * C + c0 + tc));
            tile[r][tc + 0] = v[0];
            tile[r][tc + 1] = v[1];
            tile[r][tc + 2] = v[2];
            tile[r][tc + 3] = v[3];
        }
        __syncthreads();
        int cc = threadIdx.x >> 3;
        int rr = (threadIdx.x & 7) * 8;
        #pragma unroll
        for (int i = 0; i < 2; ++i) {
            int c = cc + i * 32;
            ushort8v o;
            #pragma unroll
            for (int j = 0; j < 8; ++j) o[j] = f2b(tile[rr + j][c]);
            *(ushort8v*)(out + (size_t)(c0 + c) * R + r0 + rr) = o;
        }
    }
}

// ---------------- assign rows (offsets folded in; block 0 publishes off[]) ----------------
__global__ __launch_bounds__(256) void assign_kernel(
    const int* __restrict__ e0a, const int* __restrict__ e1a,
    const int* __restrict__ counts, int* __restrict__ fill, int* __restrict__ offg,
    int* __restrict__ row0, int* __restrict__ row1, int* __restrict__ row_token)
{
    __shared__ int off[9];
    if (threadIdx.x == 0) {
        int o = 0;
        #pragma unroll
        for (int e = 0; e < 8; ++e) { off[e] = o; o += (counts[e] + 127) & ~127; }
        off[8] = o;
        if (blockIdx.x == 0) {
            #pragma unroll
            for (int i = 0; i < 9; ++i) offg[i] = off[i];
        }
    }
    __syncthreads();
    int t = blockIdx.x * 256 + threadIdx.x;
    if (t >= T_TOKENS) return;
    int e0 = e0a[t];
    int r0 = off[e0] + atomicAdd(&fill[e0], 1);
    row0[t] = r0; row_token[r0] = t;
    int e1 = e1a[t];
    int r1 = off[e1] + atomicAdd(&fill[e1], 1);
    row1[t] = r1; row_token[r1] = t;
}

// ---------------- gather x rows -> bf16 X_perm (zeros in padding rows) ----------------
__global__ __launch_bounds__(256) void gather_kernel(
    const float* __restrict__ x, const int* __restrict__ row_token, ushort* __restrict__ Xp)
{
    int r = blockIdx.x * 2 + (threadIdx.x >> 7);
    int c = (threadIdx.x & 127) * 8;
    int tok = row_token[r];
    ushort8v o;
    if (tok >= 0 && tok < T_TOKENS) {
        const float* src = x + (size_t)tok * HD + c;
        float4 v1 = *(const float4*)(src);
        float4 v2 = *(const float4*)(src + 4);
        o[0] = f2b(v1.x); o[1] = f2b(v1.y); o[2] = f2b(v1.z); o[3] = f2b(v1.w);
        o[4] = f2b(v2.x); o[5] = f2b(v2.y); o[6] = f2b(v2.z); o[7] = f2b(v2.w);
    } else {
        o = (ushort8v){0,0,0,0,0,0,0,0};
    }
    *(ushort8v*)(Xp + (size_t)r * HD + c) = o;
}

// ---------------- L4: GEMM1 (blocks 0..4351, r9-exact)  ||  W2 transpose (4352..12543) ----------------
// GEMM1 is latency-bound -> W2-transpose blocks backfill retiring CU slots and use
// the idle HBM BW. W2 source reads are nontemporal (read-once stream).
__global__ __launch_bounds__(256, 4) void gemm1_w2t_kernel(
    const ushort* __restrict__ A, const ushort* __restrict__ Bt,
    const float* __restrict__ bias, ushort* __restrict__ Out,
    const int* __restrict__ off,
    const float* __restrict__ W2, ushort* __restrict__ W2T)
{
    constexpr int K = HD, NTOT = FF;
    constexpr int NT = NTOT / 128;                       // 32
    constexpr int NWG = (FF / 128) * (NR_MAX / 128);     // 4352
    __shared__ __align__(16) char smem[32768];

    if (blockIdx.x < NWG) {
        // ---- GEMM1 path (r9-exact; lds via smem union) ----
        ushort* L = (ushort*)smem;                       // [2][2][4096] ushort
        constexpr int chunkc = NWG >> 3;                 // 544
        int cid = blockIdx.x & 7, q = blockIdx.x >> 3;
        constexpr int mloc = chunkc / NT;                // 17 (MFAST)
        int mtile = cid * mloc + q % mloc;
        int ntile = q / mloc;
        int r0 = mtile * 128;
        int total = off[8];
        if (r0 >= total) return;
        int e = 0;
        #pragma unroll
        for (int qq = 0; qq < 7; ++qq) if (r0 >= off[qq + 1]) e = qq + 1;

        int tid = threadIdx.x;
        int w = tid >> 6, lane = tid & 63;
        int wr = w >> 1, wc = w & 1;
        int lr = lane & 15, lk = lane >> 4;

        const ushort* Ab = A + (size_t)r0 * K;
        const ushort* Bb = Bt + ((size_t)e * NTOT + (size_t)ntile * 128) * K;

        auto stage = [&](const ushort* gbase, ushort* ldsbase) {
            #pragma unroll
            for (int issue = 0; issue < 2; ++issue) {
                int row = issue * 64 + w * 16 + (lane >> 2);
                int chunk = (lane & 3) ^ ((lane >> 3) & 3);
                const ushort* g = gbase + (size_t)row * K + chunk * 8;
                ushort* lp = ldsbase + (issue * 64 + w * 16) * 32;
                __builtin_amdgcn_global_load_lds(
                    (const __attribute__((address_space(1))) void*)g,
                    (__attribute__((address_space(3))) void*)lp, 16, 0, 0);
            }
        };

        stage(Ab, L + 0 * 4096);
        stage(Bb, L + 1 * 4096);

        f32x4 acc[4][4];
        #pragma unroll
        for (int mi = 0; mi < 4; ++mi)
            #pragma unroll
            for (int ni = 0; ni < 4; ++ni) acc[mi][ni] = (f32x4){0.f, 0.f, 0.f, 0.f};

        __syncthreads();

        constexpr int KT = K / 32;
        int cur = 0;
        int slot = lk ^ ((lr >> 1) & 3);
        for (int kt = 0; kt < KT; ++kt) {
            if (kt + 1 < KT) {
                stage(Ab + (kt + 1) * 32, L + ((cur ^ 1) * 2 + 0) * 4096);
                stage(Bb + (kt + 1) * 32, L + ((cur ^ 1) * 2 + 1) * 4096);
            }
            const ushort* As = L + (cur * 2 + 0) * 4096;
            const ushort* Bs = L + (cur * 2 + 1) * 4096;
            bf16x8 a[4], b[4];
            #pragma unroll
            for (int mi = 0; mi < 4; ++mi)
                a[mi] = *(const bf16x8*)(As + (wr * 64 + mi * 16 + lr) * 32 + slot * 8);
            #pragma unroll
            for (int ni = 0; ni < 4; ++ni)
                b[ni] = *(const bf16x8*)(Bs + (wc * 64 + ni * 16 + lr) * 32 + slot * 8);
            #pragma unroll
            for (int mi = 0; mi < 4; ++mi)
                #pragma unroll
                for (int ni = 0; ni < 4; ++ni)
                    acc[mi][ni] = __builtin_amdgcn_mfma_f32_16x16x32_bf16(
                        a[mi], b[ni], acc[mi][ni], 0, 0, 0);
            __syncthreads();
            cur ^= 1;
        }

        int c0 = ntile * 128 + wc * 64;
        int rbase = r0 + wr * 64;
        #pragma unroll
        for (int ni = 0; ni < 4; ++ni) {
            int n = c0 + ni * 16 + lr;
            float bv = bias[(size_t)e * NTOT + n];
            #pragma unroll
            for (int mi = 0; mi < 4; ++mi) {
                int m = rbase + mi * 16 + lk * 4;
                #pragma unroll
                for (int j = 0; j < 4; ++j) {
                    float v = acc[mi][ni][j] + bv;
                    v = fmaxf(v, 0.f);                    // ReLU
                    Out[(size_t)(m + j) * NTOT + n] = f2b(v);
                }
            }
        }
    } else {
        // ---- W2 transpose path: [FF][HD] per expert -> [HD][FF] ----
        float (*tile)[65] = (float(*)[65])smem;           // 64x65 fp32 = 16.6 KB
        int bb = blockIdx.x - NWG;
        int e = bb >> 10, tid2 = bb & 1023;
        const float* in = W2 + (size_t)e * FF * HD;
        ushort* out = W2T + (size_t)e * FF * HD;
        int R = FF, C = HD;
        int rt = tid2 >> 4, ct = tid2 & 15;
        int r0 = rt * 64, c0 = ct * 64;

        int tr = threadIdx.x >> 4;
        int tc = (threadIdx.x & 15) * 4;
        #pragma unroll
        for (int i = 0; i < 4; ++i) {
            int r = tr + i * 16;
            f32x4 v = __builtin_nontemporal_load(
                (const f32x4*)(in + (size_t)(r0 + r) * C + c0 + tc));
            tile[r][tc + 0] = v[0];
            tile[r][tc + 1] = v[1];
            tile[r][tc + 2] = v[2];
            tile[r][tc + 3] = v[3];
        }
        __syncthreads();
        int cc = threadIdx.x >> 3;
        int rr = (threadIdx.x & 7) * 8;
        #pragma unroll
        for (int i = 0; i < 2; ++i) {
            int c = cc + i * 32;
            ushort8v o;
            #pragma unroll
            for (int j = 0; j < 8; ++j) o[j] = f2b(tile[rr + j][c]);
            *(ushort8v*)(out + (size_t)(c0 + c) * R + r0 + rr) = o;
        }
    }
}

// ---------------- GEMM2: r9-proven 128x128 structure (n-fast XCD swizzle) ----------------
template<int K, int NTOT, bool RELU, bool MFAST>
__global__ __launch_bounds__(256, 4) void gemm_kernel(
    const ushort* __restrict__ A, const ushort* __restrict__ Bt,
    const float* __restrict__ bias, ushort* __restrict__ Out,
    const int* __restrict__ off)
{
    constexpr int NT = NTOT / 128;
    __shared__ __align__(16) ushort lds[2][2][128 * 32];

    int nwg = gridDim.x;
    int chunkc = nwg >> 3;
    int cid = blockIdx.x & 7, q = blockIdx.x >> 3;
    int mtile, ntile;
    if constexpr (MFAST) {
        int mloc = chunkc / NT;
        mtile = cid * mloc + q % mloc;
        ntile = q / mloc;
    } else {
        int wgid = cid * chunkc + q;
        ntile = wgid % NT;
        mtile = wgid / NT;
    }
    int r0 = mtile * 128;
    int total = off[8];
    if (r0 >= total) return;
    int e = 0;
    #pragma unroll
    for (int qq = 0; qq < 7; ++qq) if (r0 >= off[qq + 1]) e = qq + 1;

    int tid = threadIdx.x;
    int w = tid >> 6, lane = tid & 63;
    int wr = w >> 1, wc = w & 1;
    int lr = lane & 15, lk = lane >> 4;

    const ushort* Ab = A + (size_t)r0 * K;
    const ushort* Bb = Bt + ((size_t)e * NTOT + (size_t)ntile * 128) * K;

    auto stage = [&](const ushort* gbase, ushort* ldsbase) {
        #pragma unroll
        for (int issue = 0; issue < 2; ++issue) {
            int row = issue * 64 + w * 16 + (lane >> 2);
            int chunk = (lane & 3) ^ ((lane >> 3) & 3);
            const ushort* g = gbase + (size_t)row * K + chunk * 8;
            ushort* lp = ldsbase + (issue * 64 + w * 16) * 32;
            __builtin_amdgcn_global_load_lds(
                (const __attribute__((address_space(1))) void*)g,
                (__attribute__((address_space(3))) void*)lp, 16, 0, 0);
        }
    };

    stage(Ab, &lds[0][0][0]);
    stage(Bb, &lds[0][1][0]);

    f32x4 acc[4][4];
    #pragma unroll
    for (int mi = 0; mi < 4; ++mi)
        #pragma unroll
        for (int ni = 0; ni < 4; ++ni) acc[mi][ni] = (f32x4){0.f, 0.f, 0.f, 0.f};

    __syncthreads();

    constexpr int KT = K / 32;
    int cur = 0;
    int slot = lk ^ ((lr >> 1) & 3);
    for (int kt = 0; kt < KT; ++kt) {
        if (kt + 1 < KT) {
            stage(Ab + (kt + 1) * 32, &lds[cur ^ 1][0][0]);
            stage(Bb + (kt + 1) * 32, &lds[cur ^ 1][1][0]);
        }
        const ushort* As = &lds[cur][0][0];
        const ushort* Bs = &lds[cur][1][0];
        bf16x8 a[4], b[4];
        #pragma unroll
        for (int mi = 0; mi < 4; ++mi)
            a[mi] = *(const bf16x8*)(As + (wr * 64 + mi * 16 + lr) * 32 + slot * 8);
        #pragma unroll
        for (int ni = 0; ni < 4; ++ni)
            b[ni] = *(const bf16x8*)(Bs + (wc * 64 + ni * 16 + lr) * 32 + slot * 8);
        #pragma unroll
        for (int mi = 0; mi < 4; ++mi)
            #pragma unroll
            for (int ni = 0; ni < 4; ++ni)
                acc[mi][ni] = __builtin_amdgcn_mfma_f32_16x16x32_bf16(
                    a[mi], b[ni], acc[mi][ni], 0, 0, 0);
        __syncthreads();
        cur ^= 1;
    }

    int c0 = ntile * 128 + wc * 64;
    int rbase = r0 + wr * 64;
    #pragma unroll
    for (int ni = 0; ni < 4; ++ni) {
        int n = c0 + ni * 16 + lr;
        float bv = bias[(size_t)e * NTOT + n];
        #pragma unroll
        for (int mi = 0; mi < 4; ++mi) {
            int m = rbase + mi * 16 + lk * 4;
            #pragma unroll
            for (int j = 0; j < 4; ++j) {
                float v = acc[mi][ni][j] + bv;
                if (RELU) v = fmaxf(v, 0.f);
                Out[(size_t)(m + j) * NTOT + n] = f2b(v);
            }
        }
    }
}

// ---------------- combine: out[t] = w0*Y[r0] + w1*Y[r1] ----------------
__global__ __launch_bounds__(256) void combine_kernel(
    const ushort* __restrict__ Y, const int* __restrict__ row0, const int* __restrict__ row1,
    const float* __restrict__ w0a, const float* __restrict__ w1a, float* __restrict__ out)
{
    int t = blockIdx.x;
    int c = threadIdx.x * 4;
    int r0 = row0[t], r1 = row1[t];
    float w0 = w0a[t], w1 = w1a[t];
    ushort4 ya = *(const ushort4*)(Y + (size_t)r0 * HD + c);
    ushort4 yb = *(const ushort4*)(Y + (size_t)r1 * HD + c);
    float4 o;
    o.x = w0 * b2f(ya.x) + w1 * b2f(yb.x);
    o.y = w0 * b2f(ya.y) + w1 * b2f(yb.y);
    o.z = w0 * b2f(ya.z) + w1 * b2f(yb.z);
    o.w = w0 * b2f(ya.w) + w1 * b2f(yb.w);
    *(float4*)(out + (size_t)t * HD + c) = o;
}

// ---------------- workspace layout ----------------
#define WSA(x) (((x) + 255) & ~(size_t)255)
static constexpr size_t OFF_COUNTS = 0;
static constexpr size_t OFF_FILL   = 64;
static constexpr size_t OFF_OFF    = 128;
static constexpr size_t OFF_E0     = 256;
static constexpr size_t OFF_E1     = OFF_E0 + (size_t)T_TOKENS * 4;
static constexpr size_t OFF_W0     = OFF_E1 + (size_t)T_TOKENS * 4;
static constexpr size_t OFF_W1A    = OFF_W0 + (size_t)T_TOKENS * 4;
static constexpr size_t OFF_R0     = OFF_W1A + (size_t)T_TOKENS * 4;
static constexpr size_t OFF_R1     = OFF_R0 + (size_t)T_TOKENS * 4;
static constexpr size_t OFF_RT     = OFF_R1 + (size_t)T_TOKENS * 4;
static constexpr size_t OFF_XP     = WSA(OFF_RT + (size_t)NR_MAX * 4);
static constexpr size_t OFF_W1T    = OFF_XP  + (size_t)NR_MAX * HD * 2;
static constexpr size_t OFF_W2T    = OFF_W1T + (size_t)NEXP * FF * HD * 2;
static constexpr size_t OFF_H1     = OFF_W2T + (size_t)NEXP * HD * FF * 2;
static constexpr size_t OFF_Y      = OFF_H1  + (size_t)NR_MAX * FF * 2;
static constexpr size_t WS_NEEDED  = OFF_Y   + (size_t)NR_MAX * HD * 2;

extern "C" void kernel_launch(void* const* d_in, const int* in_sizes, int n_in,
                              void* d_out, int out_size, void* d_ws, size_t ws_size,
                              hipStream_t stream) {
    (void)in_sizes; (void)n_in; (void)out_size;
    const float* x  = (const float*)d_in[0];
    const float* Wg = (const float*)d_in[1];
    const float* bg = (const float*)d_in[2];
    const float* W1 = (const float*)d_in[3];
    const float* b1 = (const float*)d_in[4];
    const float* W2 = (const float*)d_in[5];
    const float* b2 = (const float*)d_in[6];
    float* out    = (float*)d_out;
    float* logits = out + (size_t)T_TOKENS * HD;

    if (ws_size < WS_NEEDED) return;  // need ~349 MB scratch

    char* ws = (char*)d_ws;
    int*    counts = (int*)(ws + OFF_COUNTS);
    int*    fill   = (int*)(ws + OFF_FILL);
    int*    offp   = (int*)(ws + OFF_OFF);
    int*    e0a    = (int*)(ws + OFF_E0);
    int*    e1a    = (int*)(ws + OFF_E1);
    float*  w0a    = (float*)(ws + OFF_W0);
    float*  w1a    = (float*)(ws + OFF_W1A);
    int*    row0   = (int*)(ws + OFF_R0);
    int*    row1   = (int*)(ws + OFF_R1);
    int*    rowtok = (int*)(ws + OFF_RT);
    ushort* Xp     = (ushort*)(ws + OFF_XP);
    ushort* W1T    = (ushort*)(ws + OFF_W1T);
    ushort* W2T    = (ushort*)(ws + OFF_W2T);
    ushort* H1     = (ushort*)(ws + OFF_H1);
    ushort* Y      = (ushort*)(ws + OFF_Y);

    hipMemsetAsync(ws, 0, 256, stream);                         // counts/fill/off
    hipMemsetAsync(rowtok, 0xFF, (size_t)NR_MAX * 4, stream);   // row_token = -1

    gate_w1t_kernel<<<2048 + 8192, 256, 0, stream>>>(
        x, Wg, bg, logits, counts, e0a, e1a, w0a, w1a, W1, W1T);
    assign_kernel<<<T_TOKENS / 256, 256, 0, stream>>>(e0a, e1a, counts, fill, offp, row0, row1, rowtok);
    gather_kernel<<<NR_MAX / 2, 256, 0, stream>>>(x, rowtok, Xp);
    gemm1_w2t_kernel<<<(FF / 128) * (NR_MAX / 128) + 8192, 256, 0, stream>>>(
        Xp, W1T, b1, H1, offp, W2, W2T);
    gemm_kernel<FF, HD, false, false>
        <<<(HD / 128) * (NR_MAX / 128), 256, 0, stream>>>(H1, W2T, b2, Y, offp);
    combine_kernel<<<T_TOKENS, 256, 0, stream>>>(Y, row0, row1, w0a, w1a, out);
}